// Round 10
// baseline (29.726 us; speedup 1.0000x reference)
//
#include <hip/hip_runtime.h>

#define NN 256
#define MM 512
#define INF_ 256
#define OUTF 128

// N1: 128 blocks x 256 thr, FOUR rows per block (4 FMA per W load).
// b = blk>>6, q = blk&63, rows bn0..bn0+3 with bn0 = b*256 + 4q.
// Per row: H = X@W, h0 = H.a0, h1 = H.a1, cH = leaky(h0+h1).
// Also: low-row softmax stats for stat-rows n = 2q, 2q+1 (their cH pairs are
// exactly this block's 4 rows), and S-zeroing for slots 2q, 2q+1.
__global__ __launch_bounds__(256) void k_gemm(const float* __restrict__ X,
                                              const float* __restrict__ A,
                                              const float* __restrict__ W,
                                              const float* __restrict__ avec,
                                              float* __restrict__ H,
                                              float* __restrict__ h0,
                                              float* __restrict__ h1,
                                              float* __restrict__ rs0,
                                              float* __restrict__ rs1,
                                              float* __restrict__ S) {
    const int blk = blockIdx.x;          // 0..127
    const int b = blk >> 6, q = blk & 63;
    const int bn0 = b * NN + 4 * q;
    const int t = threadIdx.x;
    const int f = t & 127, kh = t >> 7;
    const int wv = t >> 6, ln = t & 63;

    __shared__ float xs[4][INF_];
    __shared__ float accs[4][256];
    __shared__ float r0[4], r1[4];
    __shared__ float sch[4];
    __shared__ float scnt[4];

    xs[0][t] = X[(bn0 + 0) * INF_ + t];
    xs[1][t] = X[(bn0 + 1) * INF_ + t];
    xs[2][t] = X[(bn0 + 2) * INF_ + t];
    xs[3][t] = X[(bn0 + 3) * INF_ + t];
    __syncthreads();

    float acc0 = 0.f, acc1 = 0.f, acc2 = 0.f, acc3 = 0.f;
    {
        const float* Wp = W + kh * 128 * OUTF + f;
        const float* x0 = xs[0] + kh * 128;
        const float* x1 = xs[1] + kh * 128;
        const float* x2 = xs[2] + kh * 128;
        const float* x3 = xs[3] + kh * 128;
#pragma unroll 8
        for (int k = 0; k < 128; ++k) {
            float w = Wp[k * OUTF];      // coalesced; shared by 4 rows
            acc0 = fmaf(x0[k], w, acc0);
            acc1 = fmaf(x1[k], w, acc1);
            acc2 = fmaf(x2[k], w, acc2);
            acc3 = fmaf(x3[k], w, acc3);
        }
    }
    accs[0][t] = acc0;
    accs[1][t] = acc1;
    accs[2][t] = acc2;
    accs[3][t] = acc3;
    __syncthreads();

    // finalize rows in two passes; pass p: threads 0..127 -> row 2p,
    // threads 128..255 -> row 2p+1 (feature tf = t&127)
#pragma unroll
    for (int pass = 0; pass < 2; ++pass) {
        const int row = 2 * pass + (t >> 7);
        const int tf = t & 127;
        float a2 = accs[row][tf] + accs[row][tf + 128];
        H[(bn0 + row) * OUTF + tf] = a2;
        float p0 = a2 * avec[tf];
        float p1 = a2 * avec[OUTF + tf];
#pragma unroll
        for (int off = 32; off >= 1; off >>= 1) {
            p0 += __shfl_down(p0, off);
            p1 += __shfl_down(p1, off);
        }
        if (ln == 0) { r0[wv] = p0; r1[wv] = p1; }
        __syncthreads();
        if (ln == 0 && (wv & 1) == 0) {  // wv 0 -> row 2p, wv 2 -> row 2p+1
            const int r = 2 * pass + (wv >> 1);
            float s0 = r0[wv] + r0[wv + 1];
            float s1 = r1[wv] + r1[wv + 1];
            h0[bn0 + r] = s0;
            h1[bn0 + r] = s1;
            float hA = s0 + s1;
            sch[r] = hA > 0.f ? hA : 0.01f * hA;   // leaky_relu 0.01
        }
        __syncthreads();
    }

    // low-row stats for n0 = 2q, n1 = 2q+1: wave w handles stat-row (w>>1),
    // m-half (w&1). Count active A entries in that half.
    {
        const int sr = wv >> 1, half = wv & 1;
        const int n = 2 * q + sr;
        const float* Ar = A + (size_t)(b * NN + n) * MM + half * 256;
        float c = 0.f;
#pragma unroll
        for (int i = 0; i < 4; ++i) c += Ar[ln + 64 * i];
#pragma unroll
        for (int off = 32; off >= 1; off >>= 1) c += __shfl_xor(c, off);
        if (ln == 0) scnt[wv] = c;
        __syncthreads();
        if (t < 2) {
            const int j = t;             // stat-row index
            float c0 = scnt[2 * j], c1 = scnt[2 * j + 1];
            float ch0 = sch[2 * j], ch1 = sch[2 * j + 1];
            float mx = fmaxf(c0 > 0.f ? ch0 : -INFINITY,
                             c1 > 0.f ? ch1 : -INFINITY);
            float e0 = c0 > 0.f ? expf(ch0 - mx) : 0.f;
            float e1 = c1 > 0.f ? expf(ch1 - mx) : 0.f;
            float inv = 1.f / (c0 * e0 + c1 * e1);
            const int bn = b * NN + 2 * q + j;
            rs0[bn] = e0 * inv;
            rs1[bn] = e1 * inv;
            S[b * 128 + 2 * q + j] = 0.f;   // zero S slot for N2's atomics
        }
    }
}

// N2: 32 blocks (b = blk>>4, mq = blk&15): em cols [32mq,32mq+32) -> g slots
// 16mq..16mq+15 (dup +256), then atomicAdd partial S[b,n] for high rows.
__global__ __launch_bounds__(256) void k_emg(const float* __restrict__ A,
                                             const float* __restrict__ h0,
                                             const float* __restrict__ h1,
                                             float* __restrict__ g,
                                             float* __restrict__ S) {
    const int blk = blockIdx.x;
    const int t = threadIdx.x;
    const int b = blk >> 4, mq = blk & 15;
    const int m_l = t & 31, n_l = t >> 5;
    __shared__ float sh0[NN], sh1[NN];
    __shared__ float sd[256], ss0[256], ss1[256];
    __shared__ float se0[32], se1[32], sg[16];
    sh0[t] = h0[b * NN + t];
    sh1[t] = h1[b * NN + t];
    __syncthreads();
    const float* Ap = A + (size_t)b * NN * MM + mq * 32 + m_l;
    float d = 0.f, s0 = 0.f, s1 = 0.f;
#pragma unroll 8
    for (int i = 0; i < 32; ++i) {
        int n = n_l * 32 + i;
        float av = Ap[n * MM];          // coalesced across m_l
        d += av;
        s0 += av * sh0[n];
        s1 += av * sh1[n];
    }
    sd[t] = d; ss0[t] = s0; ss1[t] = s1;
    __syncthreads();
    if (t < 32) {
        float D = 0.f, S0 = 0.f, S1 = 0.f;
#pragma unroll
        for (int j = 0; j < 8; ++j) {
            D  += sd[j * 32 + t];
            S0 += ss0[j * 32 + t];
            S1 += ss1[j * 32 + t];
        }
        if (D == 0.f) D = 1.f;
        se0[t] = S0 / D;                // em0[32mq+t]
        se1[t] = S1 / D;                // em1[32mq+t]
    }
    __syncthreads();
    if (t < 16) {
        // g[16mq+u] = exp(leaky(em0[32mq+2u] + em1[32mq+2u+1]))
        float v = se0[2 * t] + se1[2 * t + 1];
        v = v > 0.f ? v : 0.01f * v;
        float gv = expf(v);
        g[b * MM + 16 * mq + t] = gv;
        g[b * MM + 256 + 16 * mq + t] = gv;
        sg[t] = gv;
    }
    __syncthreads();
    // S partials for high rows, local g only (order-independent atomics)
    {
        const int u = t & 15, ng = t >> 4;   // 16 col-lanes x 16 n-groups
        const float gv = sg[u];
        const float* Alo = A + (size_t)b * NN * MM + 16 * mq + u;
#pragma unroll
        for (int step = 0; step < 8; ++step) {
            int n = 128 + ng + 16 * step;
            const float* Ar = Alo + (size_t)n * MM;
            float val = gv * (Ar[0] + Ar[256]);
            val += __shfl_xor(val, 1);
            val += __shfl_xor(val, 2);
            val += __shfl_xor(val, 4);
            val += __shfl_xor(val, 8);
            if (u == 0) atomicAdd(&S[b * 128 + n - 128], val);
        }
    }
}

// N3: out[b,m,f] = sum_{n<128} A*w*H + g[m] * sum_{n>=128} A*(1/S_n)*H.
// 128 blocks x 256 thr, EIGHT m-columns per block (8 FMA per H load).
// b = blk>>6, mo = blk&63, m_base = 8*mo. Thread = (mg = t>>7 picks the
// m-quad, nh = (t>>6)&1 picks the n-half, f2 = t&63 float2-feature).
__global__ __launch_bounds__(256) void k_out(const float* __restrict__ A,
                                             const float* __restrict__ H,
                                             const float* __restrict__ g,
                                             const float* __restrict__ rs0,
                                             const float* __restrict__ rs1,
                                             const float* __restrict__ S,
                                             float* __restrict__ out) {
    __shared__ float sW[NN];
    __shared__ float sA[8][NN];
    __shared__ float2 sacc[2][8][64];
    const int blk = blockIdx.x;
    const int b = blk >> 6, mo = blk & 63;
    const int m_base = 8 * mo;
    const int t = threadIdx.x;
    if (t < 128) {
        sW[t] = ((mo < 32) ? rs0 : rs1)[b * NN + t];   // low-row weight half
    } else {
        sW[t] = 1.f / S[b * 128 + (t - 128)];          // high-row 1/S_n
    }
    {
        const float4* Ar = (const float4*)(A + (size_t)(b * NN + t) * MM + m_base);
        float4 a0 = Ar[0], a1 = Ar[1];
        sA[0][t] = a0.x; sA[1][t] = a0.y; sA[2][t] = a0.z; sA[3][t] = a0.w;
        sA[4][t] = a1.x; sA[5][t] = a1.y; sA[6][t] = a1.z; sA[7][t] = a1.w;
    }
    __syncthreads();
    const int f2 = t & 63;
    const int nh = (t >> 6) & 1;
    const int mg = t >> 7;                 // quad {4mg..4mg+3}
    const float* sA0 = sA[4 * mg];
    const float* sA1 = sA[4 * mg + 1];
    const float* sA2 = sA[4 * mg + 2];
    const float* sA3 = sA[4 * mg + 3];
    const float2* H2 = (const float2*)H + (size_t)b * NN * 64 + f2;
    float2 accA = {0.f, 0.f}, accB = {0.f, 0.f};
    float2 accC = {0.f, 0.f}, accD = {0.f, 0.f};
#pragma unroll 8
    for (int i = 0; i < 128; ++i) {
        int n = nh * 128 + i;
        float w = sW[n];                   // LDS broadcasts (wave-uniform)
        float2 hv = H2[n * 64];            // coalesced 8B/lane
        float c0 = sA0[n] * w;
        float c1 = sA1[n] * w;
        float c2 = sA2[n] * w;
        float c3 = sA3[n] * w;
        accA.x = fmaf(c0, hv.x, accA.x); accA.y = fmaf(c0, hv.y, accA.y);
        accB.x = fmaf(c1, hv.x, accB.x); accB.y = fmaf(c1, hv.y, accB.y);
        accC.x = fmaf(c2, hv.x, accC.x); accC.y = fmaf(c2, hv.y, accC.y);
        accD.x = fmaf(c3, hv.x, accD.x); accD.y = fmaf(c3, hv.y, accD.y);
    }
    sacc[nh][4 * mg + 0][f2] = accA;
    sacc[nh][4 * mg + 1][f2] = accB;
    sacc[nh][4 * mg + 2][f2] = accC;
    sacc[nh][4 * mg + 3][f2] = accD;
    __syncthreads();
    // write 8m x 64f2 outputs with 256 threads: ml = t>>5, f2b = t&31 (+32)
    {
        const int ml = t >> 5, f2b = t & 31;
        const int m = m_base + ml;
        const float eE = g[b * MM + m];    // = exp(eLow[m])
#pragma unroll
        for (int s = 0; s < 2; ++s) {
            const int fx = f2b + 32 * s;
            float2 lo = sacc[0][ml][fx];
            float2 hi = sacc[1][ml][fx];
            float2 r;
            r.x = lo.x + eE * hi.x;
            r.y = lo.y + eE * hi.y;
            ((float2*)out)[((size_t)b * MM + m) * 64 + fx] = r;
        }
    }
}

extern "C" void kernel_launch(void* const* d_in, const int* in_sizes, int n_in,
                              void* d_out, int out_size, void* d_ws, size_t ws_size,
                              hipStream_t stream) {
    const float* X = (const float*)d_in[0];
    const float* A = (const float*)d_in[1];
    const float* W = (const float*)d_in[2];
    const float* a = (const float*)d_in[3];
    float* out = (float*)d_out;
    float* ws = (float*)d_ws;

    float* H   = ws;            // B*N*OUTF = 65536
    float* h0  = ws + 65536;    // 512
    float* h1  = ws + 66048;    // 512
    float* g   = ws + 66560;    // B*M = 1024
    float* rs0 = ws + 67584;    // B*N = 512 (low halves used)
    float* rs1 = ws + 68096;    // B*N = 512
    float* S   = ws + 68608;    // B*128 = 256 (high-row softmax denominators)

    k_gemm<<<128, 256, 0, stream>>>(X, A, W, a, H, h0, h1, rs0, rs1, S);
    k_emg<<<32, 256, 0, stream>>>(A, h0, h1, g, S);
    k_out<<<128, 256, 0, stream>>>(A, H, g, rs0, rs1, S, out);
}

// Round 11
// 23.891 us; speedup vs baseline: 1.2442x; 1.2442x over previous
//
#include <hip/hip_runtime.h>

#define NN 256
#define MM 512
#define INF_ 256
#define OUTF 128

// N1: 256 blocks x 256 thr, two rows per block (shared W loads).
// Thread layout: f4 = t&31 (features 4f4..4f4+3), kg = t>>5 (8 K-groups x 32).
// 32-iter loop, float4 W loads (16B/lane), 8 FMA/load. LDS-combine K-groups.
// Per row: H, h0 = H.a0, h1 = H.a1, cH = leaky(h0+h1); rows n>=128 zero S.
__global__ __launch_bounds__(256) void k_gemm(const float* __restrict__ X,
                                              const float* __restrict__ W,
                                              const float* __restrict__ avec,
                                              float* __restrict__ H,
                                              float* __restrict__ h0,
                                              float* __restrict__ h1,
                                              float* __restrict__ cH,
                                              float* __restrict__ S) {
    const int blk = blockIdx.x;          // 0..255
    const int t = threadIdx.x;
    const int bn0 = blk * 2;
    __shared__ float xs[2][INF_];
    __shared__ float4 sacc[2][8][32];
    xs[0][t] = X[bn0 * INF_ + t];
    xs[1][t] = X[(bn0 + 1) * INF_ + t];
    __syncthreads();

    const int f4 = t & 31, kg = t >> 5;
    const float4* W4 = (const float4*)W;
    float4 acc0 = {0.f, 0.f, 0.f, 0.f}, acc1 = {0.f, 0.f, 0.f, 0.f};
    const int k0 = kg * 32;
#pragma unroll 8
    for (int i = 0; i < 32; ++i) {
        const int k = k0 + i;
        float4 w = W4[k * 32 + f4];      // coalesced 16B/lane
        float x0v = xs[0][k], x1v = xs[1][k];   // LDS broadcasts
        acc0.x = fmaf(x0v, w.x, acc0.x); acc0.y = fmaf(x0v, w.y, acc0.y);
        acc0.z = fmaf(x0v, w.z, acc0.z); acc0.w = fmaf(x0v, w.w, acc0.w);
        acc1.x = fmaf(x1v, w.x, acc1.x); acc1.y = fmaf(x1v, w.y, acc1.y);
        acc1.z = fmaf(x1v, w.z, acc1.z); acc1.w = fmaf(x1v, w.w, acc1.w);
    }
    sacc[0][kg][f4] = acc0;
    sacc[1][kg][f4] = acc1;
    __syncthreads();

    if (t < 64) {                        // wave 0: lanes 0..31 row0, 32..63 row1
        const int r = t >> 5, fb = t & 31;
        float4 s = {0.f, 0.f, 0.f, 0.f};
#pragma unroll
        for (int j = 0; j < 8; ++j) {
            float4 v = sacc[r][j][fb];
            s.x += v.x; s.y += v.y; s.z += v.z; s.w += v.w;
        }
        ((float4*)H)[(bn0 + r) * 32 + fb] = s;
        const float4* av4 = (const float4*)avec;
        float4 a0 = av4[fb], a1 = av4[32 + fb];
        float p0 = s.x*a0.x + s.y*a0.y + s.z*a0.z + s.w*a0.w;
        float p1 = s.x*a1.x + s.y*a1.y + s.z*a1.z + s.w*a1.w;
#pragma unroll
        for (int off = 16; off >= 1; off >>= 1) {   // stays within 32-lane half
            p0 += __shfl_xor(p0, off);
            p1 += __shfl_xor(p1, off);
        }
        if ((t & 31) == 0) {
            const int bn = bn0 + r;
            h0[bn] = p0;
            h1[bn] = p1;
            float hA = p0 + p1;
            cH[bn] = hA > 0.f ? hA : 0.01f * hA;   // leaky_relu 0.01
            const int n = bn & 255;
            if (n >= 128) S[(bn >> 8) * 128 + n - 128] = 0.f;
        }
    }
}

// N2: 96 blocks (R9's proven version).
// Blocks 0..31 (b = blk>>4, mq = blk&15): em cols [32mq,32mq+32) -> g slots
//   16mq..16mq+15 (dup +256), then atomicAdd partial S[b,n] for high rows.
// Blocks 32..95: low-row (n<128) exact 2-value softmax weights -> rs0/rs1.
__global__ __launch_bounds__(256) void k_emg(const float* __restrict__ A,
                                             const float* __restrict__ h0,
                                             const float* __restrict__ h1,
                                             const float* __restrict__ cH,
                                             float* __restrict__ g,
                                             float* __restrict__ rs0,
                                             float* __restrict__ rs1,
                                             float* __restrict__ S) {
    const int blk = blockIdx.x;
    const int t = threadIdx.x;
    if (blk < 32) {
        const int b = blk >> 4, mq = blk & 15;
        const int m_l = t & 31, n_l = t >> 5;
        __shared__ float sh0[NN], sh1[NN];
        __shared__ float sd[256], ss0[256], ss1[256];
        __shared__ float se0[32], se1[32], sg[16];
        sh0[t] = h0[b * NN + t];
        sh1[t] = h1[b * NN + t];
        __syncthreads();
        const float* Ap = A + (size_t)b * NN * MM + mq * 32 + m_l;
        float d = 0.f, s0 = 0.f, s1 = 0.f;
#pragma unroll 8
        for (int i = 0; i < 32; ++i) {
            int n = n_l * 32 + i;
            float av = Ap[n * MM];          // coalesced across m_l
            d += av;
            s0 += av * sh0[n];
            s1 += av * sh1[n];
        }
        sd[t] = d; ss0[t] = s0; ss1[t] = s1;
        __syncthreads();
        if (t < 32) {
            float D = 0.f, S0 = 0.f, S1 = 0.f;
#pragma unroll
            for (int j = 0; j < 8; ++j) {
                D  += sd[j * 32 + t];
                S0 += ss0[j * 32 + t];
                S1 += ss1[j * 32 + t];
            }
            if (D == 0.f) D = 1.f;
            se0[t] = S0 / D;                // em0[32mq+t]
            se1[t] = S1 / D;                // em1[32mq+t]
        }
        __syncthreads();
        if (t < 16) {
            // g[16mq+u] = exp(leaky(em0[32mq+2u] + em1[32mq+2u+1]))
            float v = se0[2 * t] + se1[2 * t + 1];
            v = v > 0.f ? v : 0.01f * v;
            float gv = expf(v);
            g[b * MM + 16 * mq + t] = gv;
            g[b * MM + 256 + 16 * mq + t] = gv;
            sg[t] = gv;
        }
        __syncthreads();
        // S partials for high rows, local g only (order-independent atomics)
        {
            const int u = t & 15, ng = t >> 4;   // 16 col-lanes x 16 n-groups
            const float gv = sg[u];
            const float* Alo = A + (size_t)b * NN * MM + 16 * mq + u;
#pragma unroll
            for (int step = 0; step < 8; ++step) {
                int n = 128 + ng + 16 * step;
                const float* Ar = Alo + (size_t)n * MM;
                float val = gv * (Ar[0] + Ar[256]);
                val += __shfl_xor(val, 1);
                val += __shfl_xor(val, 2);
                val += __shfl_xor(val, 4);
                val += __shfl_xor(val, 8);
                if (u == 0) atomicAdd(&S[b * 128 + n - 128], val);
            }
        }
    } else {
        // low-row stats: l = (blk-32)*4 + wave -> b = l>>7, n = l&127
        const int wv = t >> 6, lane = t & 63;
        const int l = (blk - 32) * 4 + wv;
        const int b = l >> 7, n = l & 127;
        const int bn = b * NN + n;
        const float* Ar = A + (size_t)bn * MM;
        float c0 = 0.f, c1 = 0.f;
#pragma unroll
        for (int i = 0; i < 8; ++i) {
            float av = Ar[lane + 64 * i];
            if (i < 4) c0 += av; else c1 += av;
        }
#pragma unroll
        for (int off = 32; off >= 1; off >>= 1) {
            c0 += __shfl_xor(c0, off);
            c1 += __shfl_xor(c1, off);
        }
        if (lane == 0) {
            float ch0 = cH[b * NN + 2 * n];
            float ch1 = cH[b * NN + 2 * n + 1];
            float mx = fmaxf(c0 > 0.f ? ch0 : -INFINITY,
                             c1 > 0.f ? ch1 : -INFINITY);
            float e0 = c0 > 0.f ? expf(ch0 - mx) : 0.f;
            float e1 = c1 > 0.f ? expf(ch1 - mx) : 0.f;
            float inv = 1.f / (c0 * e0 + c1 * e1);
            rs0[bn] = e0 * inv;
            rs1[bn] = e1 * inv;
        }
    }
}

// N3: out[b,m,f] = sum_{n<128} A*w*H + g[m] * sum_{n>=128} A*(1/S_n)*H.
// 256 blocks x 256 thr, four m-columns per block.
// Thread layout: f4 = t&31 (features 4f4..4f4+3), ng = t>>5 (8 n-groups x 32;
// groups 0..3 = low n-half, 4..7 = high). 32-iter loop, float4 H loads,
// 16 FMA/load. Epilogue: r = lo + eE*hi per m, float4 write.
__global__ __launch_bounds__(256) void k_out(const float* __restrict__ A,
                                             const float* __restrict__ H,
                                             const float* __restrict__ g,
                                             const float* __restrict__ rs0,
                                             const float* __restrict__ rs1,
                                             const float* __restrict__ S,
                                             float* __restrict__ out) {
    __shared__ float sW[NN];
    __shared__ float sA[4][NN];
    __shared__ float4 sacc[8][4][32];      // 16 KB
    const int blk = blockIdx.x;
    const int b = blk >> 7, mq = blk & 127;
    const int m_base = 4 * mq;
    const int t = threadIdx.x;
    if (t < 128) {
        sW[t] = ((mq < 64) ? rs0 : rs1)[b * NN + t];   // low-row weight half
    } else {
        sW[t] = 1.f / S[b * 128 + (t - 128)];          // high-row 1/S_n
    }
    {
        const float4* Ar = (const float4*)(A + (size_t)(b * NN + t) * MM + m_base);
        float4 a = Ar[0];
        sA[0][t] = a.x; sA[1][t] = a.y; sA[2][t] = a.z; sA[3][t] = a.w;
    }
    __syncthreads();
    const int f4 = t & 31, ng = t >> 5;
    const float4* H4 = (const float4*)H + (size_t)b * NN * 32 + f4;
    float4 A0 = {0.f,0.f,0.f,0.f}, A1 = {0.f,0.f,0.f,0.f};
    float4 A2 = {0.f,0.f,0.f,0.f}, A3 = {0.f,0.f,0.f,0.f};
    const int n0 = ng * 32;
#pragma unroll 8
    for (int i = 0; i < 32; ++i) {
        const int n = n0 + i;
        float w = sW[n];                   // LDS broadcast
        float4 hv = H4[n * 32];            // coalesced 16B/lane
        float c0 = sA[0][n] * w;
        float c1 = sA[1][n] * w;
        float c2 = sA[2][n] * w;
        float c3 = sA[3][n] * w;
        A0.x = fmaf(c0, hv.x, A0.x); A0.y = fmaf(c0, hv.y, A0.y);
        A0.z = fmaf(c0, hv.z, A0.z); A0.w = fmaf(c0, hv.w, A0.w);
        A1.x = fmaf(c1, hv.x, A1.x); A1.y = fmaf(c1, hv.y, A1.y);
        A1.z = fmaf(c1, hv.z, A1.z); A1.w = fmaf(c1, hv.w, A1.w);
        A2.x = fmaf(c2, hv.x, A2.x); A2.y = fmaf(c2, hv.y, A2.y);
        A2.z = fmaf(c2, hv.z, A2.z); A2.w = fmaf(c2, hv.w, A2.w);
        A3.x = fmaf(c3, hv.x, A3.x); A3.y = fmaf(c3, hv.y, A3.y);
        A3.z = fmaf(c3, hv.z, A3.z); A3.w = fmaf(c3, hv.w, A3.w);
    }
    sacc[ng][0][f4] = A0;
    sacc[ng][1][f4] = A1;
    sacc[ng][2][f4] = A2;
    sacc[ng][3][f4] = A3;
    __syncthreads();
    if (t < 128) {
        const int ml = t >> 5, fb = t & 31;
        float4 lo = {0.f,0.f,0.f,0.f}, hi = {0.f,0.f,0.f,0.f};
#pragma unroll
        for (int j = 0; j < 4; ++j) {
            float4 vl = sacc[j][ml][fb];
            float4 vh = sacc[4 + j][ml][fb];
            lo.x += vl.x; lo.y += vl.y; lo.z += vl.z; lo.w += vl.w;
            hi.x += vh.x; hi.y += vh.y; hi.z += vh.z; hi.w += vh.w;
        }
        const int m = m_base + ml;
        const float eE = g[b * MM + m];    // = exp(eLow[m])
        float4 r;
        r.x = lo.x + eE * hi.x;
        r.y = lo.y + eE * hi.y;
        r.z = lo.z + eE * hi.z;
        r.w = lo.w + eE * hi.w;
        ((float4*)out)[((size_t)b * MM + m) * 32 + fb] = r;
    }
}

extern "C" void kernel_launch(void* const* d_in, const int* in_sizes, int n_in,
                              void* d_out, int out_size, void* d_ws, size_t ws_size,
                              hipStream_t stream) {
    const float* X = (const float*)d_in[0];
    const float* A = (const float*)d_in[1];
    const float* W = (const float*)d_in[2];
    const float* a = (const float*)d_in[3];
    float* out = (float*)d_out;
    float* ws = (float*)d_ws;

    float* H   = ws;            // B*N*OUTF = 65536
    float* h0  = ws + 65536;    // 512
    float* h1  = ws + 66048;    // 512
    float* cH  = ws + 66560;    // 512
    float* g   = ws + 67072;    // B*M = 1024
    float* rs0 = ws + 68096;    // B*N = 512 (low halves used)
    float* rs1 = ws + 68608;    // B*N = 512
    float* S   = ws + 69120;    // B*128 = 256 (high-row softmax denominators)

    k_gemm<<<256, 256, 0, stream>>>(X, W, a, H, h0, h1, cH, S);
    k_emg<<<96, 256, 0, stream>>>(A, h0, h1, cH, g, rs0, rs1, S);
    k_out<<<256, 256, 0, stream>>>(A, H, g, rs0, rs1, S, out);
}

// Round 12
// 21.246 us; speedup vs baseline: 1.3991x; 1.1245x over previous
//
#include <hip/hip_runtime.h>

#define NN 256
#define MM 512
#define INF_ 256
#define OUTF 128

// N1: 256 blocks x 256 thr, two rows per block (rows 2q, 2q+1; q = blk&127).
// Main: H = X@W via f4 = t&31 (features 4f4..4f4+3), kg = t>>5 (8 K-groups),
// float4 W loads, LDS-combine. Epilogue wave0: combine + H + a-dots ->
// h0/h1/cH(LDS). Epilogue wave1 (concurrent): A[b,q,:] half-counts.
// Finalize t==0: exact 2-value low-row softmax weights rs0/rs1[b,q]; S-zero.
__global__ __launch_bounds__(256) void k_gemm(const float* __restrict__ X,
                                              const float* __restrict__ A,
                                              const float* __restrict__ W,
                                              const float* __restrict__ avec,
                                              float* __restrict__ H,
                                              float* __restrict__ h0,
                                              float* __restrict__ h1,
                                              float* __restrict__ rs0,
                                              float* __restrict__ rs1,
                                              float* __restrict__ S) {
    const int blk = blockIdx.x;          // 0..255
    const int t = threadIdx.x;
    const int b = blk >> 7, q = blk & 127;
    const int bn0 = blk * 2;             // = b*256 + 2q
    __shared__ float xs[2][INF_];
    __shared__ float4 sacc[2][8][32];
    __shared__ float sch[2];
    __shared__ float scnt[2];
    xs[0][t] = X[bn0 * INF_ + t];
    xs[1][t] = X[(bn0 + 1) * INF_ + t];
    __syncthreads();

    const int f4 = t & 31, kg = t >> 5;
    const float4* W4 = (const float4*)W;
    float4 acc0 = {0.f, 0.f, 0.f, 0.f}, acc1 = {0.f, 0.f, 0.f, 0.f};
    const int k0 = kg * 32;
#pragma unroll 8
    for (int i = 0; i < 32; ++i) {
        const int k = k0 + i;
        float4 w = W4[k * 32 + f4];      // coalesced 16B/lane
        float x0v = xs[0][k], x1v = xs[1][k];   // LDS broadcasts
        acc0.x = fmaf(x0v, w.x, acc0.x); acc0.y = fmaf(x0v, w.y, acc0.y);
        acc0.z = fmaf(x0v, w.z, acc0.z); acc0.w = fmaf(x0v, w.w, acc0.w);
        acc1.x = fmaf(x1v, w.x, acc1.x); acc1.y = fmaf(x1v, w.y, acc1.y);
        acc1.z = fmaf(x1v, w.z, acc1.z); acc1.w = fmaf(x1v, w.w, acc1.w);
    }
    sacc[0][kg][f4] = acc0;
    sacc[1][kg][f4] = acc1;
    __syncthreads();

    if (t < 64) {                        // wave0: lanes 0..31 row0, 32..63 row1
        const int r = t >> 5, fb = t & 31;
        float4 s = {0.f, 0.f, 0.f, 0.f};
#pragma unroll
        for (int j = 0; j < 8; ++j) {
            float4 v = sacc[r][j][fb];
            s.x += v.x; s.y += v.y; s.z += v.z; s.w += v.w;
        }
        ((float4*)H)[(bn0 + r) * 32 + fb] = s;
        const float4* av4 = (const float4*)avec;
        float4 a0 = av4[fb], a1 = av4[32 + fb];
        float p0 = s.x*a0.x + s.y*a0.y + s.z*a0.z + s.w*a0.w;
        float p1 = s.x*a1.x + s.y*a1.y + s.z*a1.z + s.w*a1.w;
#pragma unroll
        for (int off = 16; off >= 1; off >>= 1) {   // stays within 32-lane half
            p0 += __shfl_xor(p0, off);
            p1 += __shfl_xor(p1, off);
        }
        if ((t & 31) == 0) {
            const int bn = bn0 + r;
            h0[bn] = p0;
            h1[bn] = p1;
            float hA = p0 + p1;
            sch[r] = hA > 0.f ? hA : 0.01f * hA;   // leaky_relu 0.01
        }
    } else if (t < 128) {                // wave1: A[b,q,:] half-counts
        const int l = t - 64;
        const float* Ar = A + (size_t)(b * NN + q) * MM;
        float c0 = 0.f, c1 = 0.f;
#pragma unroll
        for (int i = 0; i < 8; ++i) {
            float av = Ar[l + 64 * i];
            if (i < 4) c0 += av; else c1 += av;
        }
#pragma unroll
        for (int off = 32; off >= 1; off >>= 1) {
            c0 += __shfl_xor(c0, off);
            c1 += __shfl_xor(c1, off);
        }
        if (l == 0) { scnt[0] = c0; scnt[1] = c1; }
    }
    __syncthreads();
    if (t == 0) {
        const float c0 = scnt[0], c1 = scnt[1];
        const float ch0 = sch[0], ch1 = sch[1];
        float mx = fmaxf(c0 > 0.f ? ch0 : -INFINITY,
                         c1 > 0.f ? ch1 : -INFINITY);
        float e0 = c0 > 0.f ? expf(ch0 - mx) : 0.f;
        float e1 = c1 > 0.f ? expf(ch1 - mx) : 0.f;
        float inv = 1.f / (c0 * e0 + c1 * e1);
        rs0[b * NN + q] = e0 * inv;
        rs1[b * NN + q] = e1 * inv;
        S[b * 128 + q] = 0.f;            // zero S slot for N2's atomics
    }
}

// N2: 64 blocks (b = blk>>5, mq = blk&31): em cols [16mq,16mq+16) -> g slots
// 8mq..8mq+7 (dup +256), then atomicAdd partial S[b,n] for high rows.
// 256 thr: m_l = t&15 (16 cols), n_l = t>>4 (16 n-groups x 16).
__global__ __launch_bounds__(256) void k_emg(const float* __restrict__ A,
                                             const float* __restrict__ h0,
                                             const float* __restrict__ h1,
                                             float* __restrict__ g,
                                             float* __restrict__ S) {
    const int blk = blockIdx.x;
    const int t = threadIdx.x;
    const int b = blk >> 5, mq = blk & 31;
    const int m_l = t & 15, n_l = t >> 4;
    __shared__ float sh0[NN], sh1[NN];
    __shared__ float sd[256], ss0[256], ss1[256];
    __shared__ float se0[16], se1[16], sg[8];
    sh0[t] = h0[b * NN + t];
    sh1[t] = h1[b * NN + t];
    __syncthreads();
    const float* Ap = A + (size_t)b * NN * MM + mq * 16 + m_l;
    float d = 0.f, s0 = 0.f, s1 = 0.f;
#pragma unroll 8
    for (int i = 0; i < 16; ++i) {
        int n = n_l * 16 + i;
        float av = Ap[n * MM];          // coalesced across m_l
        d += av;
        s0 += av * sh0[n];
        s1 += av * sh1[n];
    }
    sd[t] = d; ss0[t] = s0; ss1[t] = s1;
    __syncthreads();
    if (t < 16) {
        float D = 0.f, S0 = 0.f, S1 = 0.f;
#pragma unroll
        for (int j = 0; j < 16; ++j) {
            D  += sd[j * 16 + t];
            S0 += ss0[j * 16 + t];
            S1 += ss1[j * 16 + t];
        }
        if (D == 0.f) D = 1.f;
        se0[t] = S0 / D;                // em0[16mq+t]
        se1[t] = S1 / D;                // em1[16mq+t]
    }
    __syncthreads();
    if (t < 8) {
        // g[8mq+u] = exp(leaky(em0[16mq+2u] + em1[16mq+2u+1]))
        float v = se0[2 * t] + se1[2 * t + 1];
        v = v > 0.f ? v : 0.01f * v;
        float gv = expf(v);
        g[b * MM + 8 * mq + t] = gv;
        g[b * MM + 256 + 8 * mq + t] = gv;
        sg[t] = gv;
    }
    __syncthreads();
    // S partials for high rows, local g only (order-independent atomics).
    // u = t&7 (8 g-cols), ng = t>>3 (32 n-groups x 4 steps).
    {
        const int u = t & 7, ng = t >> 3;
        const float gv = sg[u];
        const float* Alo = A + (size_t)b * NN * MM + 8 * mq + u;
#pragma unroll
        for (int step = 0; step < 4; ++step) {
            int n = 128 + ng + 32 * step;
            const float* Ar = Alo + (size_t)n * MM;
            float val = gv * (Ar[0] + Ar[256]);
            val += __shfl_xor(val, 1);
            val += __shfl_xor(val, 2);
            val += __shfl_xor(val, 4);
            if (u == 0) atomicAdd(&S[b * 128 + n - 128], val);
        }
    }
}

// N3: out[b,m,f] = sum_{n<128} A*w*H + g[m] * sum_{n>=128} A*(1/S_n)*H.
// 256 blocks x 256 thr, four m-columns per block (unchanged from R11).
__global__ __launch_bounds__(256) void k_out(const float* __restrict__ A,
                                             const float* __restrict__ H,
                                             const float* __restrict__ g,
                                             const float* __restrict__ rs0,
                                             const float* __restrict__ rs1,
                                             const float* __restrict__ S,
                                             float* __restrict__ out) {
    __shared__ float sW[NN];
    __shared__ float sA[4][NN];
    __shared__ float4 sacc[8][4][32];      // 16 KB
    const int blk = blockIdx.x;
    const int b = blk >> 7, mq = blk & 127;
    const int m_base = 4 * mq;
    const int t = threadIdx.x;
    if (t < 128) {
        sW[t] = ((mq < 64) ? rs0 : rs1)[b * NN + t];   // low-row weight half
    } else {
        sW[t] = 1.f / S[b * 128 + (t - 128)];          // high-row 1/S_n
    }
    {
        const float4* Ar = (const float4*)(A + (size_t)(b * NN + t) * MM + m_base);
        float4 a = Ar[0];
        sA[0][t] = a.x; sA[1][t] = a.y; sA[2][t] = a.z; sA[3][t] = a.w;
    }
    __syncthreads();
    const int f4 = t & 31, ng = t >> 5;
    const float4* H4 = (const float4*)H + (size_t)b * NN * 32 + f4;
    float4 A0 = {0.f,0.f,0.f,0.f}, A1 = {0.f,0.f,0.f,0.f};
    float4 A2 = {0.f,0.f,0.f,0.f}, A3 = {0.f,0.f,0.f,0.f};
    const int n0 = ng * 32;
#pragma unroll 8
    for (int i = 0; i < 32; ++i) {
        const int n = n0 + i;
        float w = sW[n];                   // LDS broadcast
        float4 hv = H4[n * 32];            // coalesced 16B/lane
        float c0 = sA[0][n] * w;
        float c1 = sA[1][n] * w;
        float c2 = sA[2][n] * w;
        float c3 = sA[3][n] * w;
        A0.x = fmaf(c0, hv.x, A0.x); A0.y = fmaf(c0, hv.y, A0.y);
        A0.z = fmaf(c0, hv.z, A0.z); A0.w = fmaf(c0, hv.w, A0.w);
        A1.x = fmaf(c1, hv.x, A1.x); A1.y = fmaf(c1, hv.y, A1.y);
        A1.z = fmaf(c1, hv.z, A1.z); A1.w = fmaf(c1, hv.w, A1.w);
        A2.x = fmaf(c2, hv.x, A2.x); A2.y = fmaf(c2, hv.y, A2.y);
        A2.z = fmaf(c2, hv.z, A2.z); A2.w = fmaf(c2, hv.w, A2.w);
        A3.x = fmaf(c3, hv.x, A3.x); A3.y = fmaf(c3, hv.y, A3.y);
        A3.z = fmaf(c3, hv.z, A3.z); A3.w = fmaf(c3, hv.w, A3.w);
    }
    sacc[ng][0][f4] = A0;
    sacc[ng][1][f4] = A1;
    sacc[ng][2][f4] = A2;
    sacc[ng][3][f4] = A3;
    __syncthreads();
    if (t < 128) {
        const int ml = t >> 5, fb = t & 31;
        float4 lo = {0.f,0.f,0.f,0.f}, hi = {0.f,0.f,0.f,0.f};
#pragma unroll
        for (int j = 0; j < 4; ++j) {
            float4 vl = sacc[j][ml][fb];
            float4 vh = sacc[4 + j][ml][fb];
            lo.x += vl.x; lo.y += vl.y; lo.z += vl.z; lo.w += vl.w;
            hi.x += vh.x; hi.y += vh.y; hi.z += vh.z; hi.w += vh.w;
        }
        const int m = m_base + ml;
        const float eE = g[b * MM + m];    // = exp(eLow[m])
        float4 r;
        r.x = lo.x + eE * hi.x;
        r.y = lo.y + eE * hi.y;
        r.z = lo.z + eE * hi.z;
        r.w = lo.w + eE * hi.w;
        ((float4*)out)[((size_t)b * MM + m) * 32 + fb] = r;
    }
}

extern "C" void kernel_launch(void* const* d_in, const int* in_sizes, int n_in,
                              void* d_out, int out_size, void* d_ws, size_t ws_size,
                              hipStream_t stream) {
    const float* X = (const float*)d_in[0];
    const float* A = (const float*)d_in[1];
    const float* W = (const float*)d_in[2];
    const float* a = (const float*)d_in[3];
    float* out = (float*)d_out;
    float* ws = (float*)d_ws;

    float* H   = ws;            // B*N*OUTF = 65536
    float* h0  = ws + 65536;    // 512
    float* h1  = ws + 66048;    // 512
    float* g   = ws + 66560;    // B*M = 1024
    float* rs0 = ws + 67584;    // B*N = 512 (low halves used)
    float* rs1 = ws + 68096;    // B*N = 512
    float* S   = ws + 68608;    // B*128 = 256 (high-row softmax denominators)

    k_gemm<<<256, 256, 0, stream>>>(X, A, W, a, H, h0, h1, rs0, rs1, S);
    k_emg<<<64, 256, 0, stream>>>(A, h0, h1, g, S);
    k_out<<<256, 256, 0, stream>>>(A, H, g, rs0, rs1, S, out);
}

// Round 13
// 21.210 us; speedup vs baseline: 1.4015x; 1.0017x over previous
//
#include <hip/hip_runtime.h>

#define NN 256
#define MM 512
#define INF_ 256
#define OUTF 128

// N1: 256 blocks x 512 thr (8 waves -> 2 waves/SIMD), two rows per block.
// f4 = t&31 (features 4f4..4f4+3), kg = t>>5 (16 K-groups x 16 iters),
// float4 W loads, LDS-combine. Epilogue wave0: combine + H + a-dots;
// wave1: A[b,q,:] half-counts. t==0: low-row softmax weights; S-zero.
__global__ __launch_bounds__(512) void k_gemm(const float* __restrict__ X,
                                              const float* __restrict__ A,
                                              const float* __restrict__ W,
                                              const float* __restrict__ avec,
                                              float* __restrict__ H,
                                              float* __restrict__ h0,
                                              float* __restrict__ h1,
                                              float* __restrict__ rs0,
                                              float* __restrict__ rs1,
                                              float* __restrict__ S) {
    const int blk = blockIdx.x;          // 0..255
    const int t = threadIdx.x;
    const int b = blk >> 7, q = blk & 127;
    const int bn0 = blk * 2;             // = b*256 + 2q
    __shared__ float xs[2][INF_];
    __shared__ float4 sacc[2][16][32];   // 16 KB
    __shared__ float sch[2];
    __shared__ float scnt[2];
    {
        const int row = t >> 8, idx = t & 255;
        xs[row][idx] = X[(bn0 + row) * INF_ + idx];
    }
    __syncthreads();

    const int f4 = t & 31, kg = t >> 5;  // kg in [0,16)
    const float4* W4 = (const float4*)W;
    float4 acc0 = {0.f, 0.f, 0.f, 0.f}, acc1 = {0.f, 0.f, 0.f, 0.f};
    const int k0 = kg * 16;
#pragma unroll 8
    for (int i = 0; i < 16; ++i) {
        const int k = k0 + i;
        float4 w = W4[k * 32 + f4];      // coalesced 16B/lane
        float x0v = xs[0][k], x1v = xs[1][k];   // LDS broadcasts
        acc0.x = fmaf(x0v, w.x, acc0.x); acc0.y = fmaf(x0v, w.y, acc0.y);
        acc0.z = fmaf(x0v, w.z, acc0.z); acc0.w = fmaf(x0v, w.w, acc0.w);
        acc1.x = fmaf(x1v, w.x, acc1.x); acc1.y = fmaf(x1v, w.y, acc1.y);
        acc1.z = fmaf(x1v, w.z, acc1.z); acc1.w = fmaf(x1v, w.w, acc1.w);
    }
    sacc[0][kg][f4] = acc0;
    sacc[1][kg][f4] = acc1;
    __syncthreads();

    if (t < 64) {                        // wave0: lanes 0..31 row0, 32..63 row1
        const int r = t >> 5, fb = t & 31;
        float4 s = {0.f, 0.f, 0.f, 0.f};
#pragma unroll
        for (int j = 0; j < 16; ++j) {
            float4 v = sacc[r][j][fb];
            s.x += v.x; s.y += v.y; s.z += v.z; s.w += v.w;
        }
        ((float4*)H)[(bn0 + r) * 32 + fb] = s;
        const float4* av4 = (const float4*)avec;
        float4 a0 = av4[fb], a1 = av4[32 + fb];
        float p0 = s.x*a0.x + s.y*a0.y + s.z*a0.z + s.w*a0.w;
        float p1 = s.x*a1.x + s.y*a1.y + s.z*a1.z + s.w*a1.w;
#pragma unroll
        for (int off = 16; off >= 1; off >>= 1) {   // stays within 32-lane half
            p0 += __shfl_xor(p0, off);
            p1 += __shfl_xor(p1, off);
        }
        if ((t & 31) == 0) {
            const int bn = bn0 + r;
            h0[bn] = p0;
            h1[bn] = p1;
            float hA = p0 + p1;
            sch[r] = hA > 0.f ? hA : 0.01f * hA;   // leaky_relu 0.01
        }
    } else if (t < 128) {                // wave1: A[b,q,:] half-counts
        const int l = t - 64;
        const float* Ar = A + (size_t)(b * NN + q) * MM;
        float c0 = 0.f, c1 = 0.f;
#pragma unroll
        for (int i = 0; i < 8; ++i) {
            float av = Ar[l + 64 * i];
            if (i < 4) c0 += av; else c1 += av;
        }
#pragma unroll
        for (int off = 32; off >= 1; off >>= 1) {
            c0 += __shfl_xor(c0, off);
            c1 += __shfl_xor(c1, off);
        }
        if (l == 0) { scnt[0] = c0; scnt[1] = c1; }
    }
    __syncthreads();
    if (t == 0) {
        const float c0 = scnt[0], c1 = scnt[1];
        const float ch0 = sch[0], ch1 = sch[1];
        float mx = fmaxf(c0 > 0.f ? ch0 : -INFINITY,
                         c1 > 0.f ? ch1 : -INFINITY);
        float e0 = c0 > 0.f ? expf(ch0 - mx) : 0.f;
        float e1 = c1 > 0.f ? expf(ch1 - mx) : 0.f;
        float inv = 1.f / (c0 * e0 + c1 * e1);
        rs0[b * NN + q] = e0 * inv;
        rs1[b * NN + q] = e1 * inv;
        S[b * 128 + q] = 0.f;            // zero S slot for N2's atomics
    }
}

// N2: 64 blocks x 512 thr (b = blk>>5, mq = blk&31): em cols [16mq,16mq+16)
// -> g slots 8mq..8mq+7 (dup +256), then atomicAdd partial S[b,n].
// em: m_l = t&15 (16 cols), n_l = t>>4 (32 n-groups x 8 iters).
__global__ __launch_bounds__(512) void k_emg(const float* __restrict__ A,
                                             const float* __restrict__ h0,
                                             const float* __restrict__ h1,
                                             float* __restrict__ g,
                                             float* __restrict__ S) {
    const int blk = blockIdx.x;
    const int t = threadIdx.x;
    const int b = blk >> 5, mq = blk & 31;
    const int m_l = t & 15, n_l = t >> 4;    // n_l in [0,32)
    __shared__ float sh0[NN], sh1[NN];
    __shared__ float sd[512], ss0[512], ss1[512];
    __shared__ float se0[16], se1[16], sg[8];
    if (t < 256) {
        sh0[t] = h0[b * NN + t];
        sh1[t] = h1[b * NN + t];
    }
    __syncthreads();
    const float* Ap = A + (size_t)b * NN * MM + mq * 16 + m_l;
    float d = 0.f, s0 = 0.f, s1 = 0.f;
#pragma unroll
    for (int i = 0; i < 8; ++i) {
        int n = n_l * 8 + i;
        float av = Ap[n * MM];          // coalesced across m_l (64B)
        d += av;
        s0 += av * sh0[n];
        s1 += av * sh1[n];
    }
    sd[t] = d; ss0[t] = s0; ss1[t] = s1;
    __syncthreads();
    if (t < 16) {
        float D = 0.f, S0 = 0.f, S1 = 0.f;
#pragma unroll
        for (int j = 0; j < 32; ++j) {
            D  += sd[j * 16 + t];
            S0 += ss0[j * 16 + t];
            S1 += ss1[j * 16 + t];
        }
        if (D == 0.f) D = 1.f;
        se0[t] = S0 / D;                // em0[16mq+t]
        se1[t] = S1 / D;                // em1[16mq+t]
    }
    __syncthreads();
    if (t < 8) {
        // g[8mq+u] = exp(leaky(em0[16mq+2u] + em1[16mq+2u+1]))
        float v = se0[2 * t] + se1[2 * t + 1];
        v = v > 0.f ? v : 0.01f * v;
        float gv = expf(v);
        g[b * MM + 8 * mq + t] = gv;
        g[b * MM + 256 + 8 * mq + t] = gv;
        sg[t] = gv;
    }
    __syncthreads();
    // S partials for high rows, local g only (order-independent atomics).
    // u = t&7 (8 g-cols), ng = t>>3 (64 n-groups x 2 steps).
    {
        const int u = t & 7, ng = t >> 3;
        const float gv = sg[u];
        const float* Alo = A + (size_t)b * NN * MM + 8 * mq + u;
#pragma unroll
        for (int step = 0; step < 2; ++step) {
            int n = 128 + ng + 64 * step;
            const float* Ar = Alo + (size_t)n * MM;
            float val = gv * (Ar[0] + Ar[256]);
            val += __shfl_xor(val, 1);
            val += __shfl_xor(val, 2);
            val += __shfl_xor(val, 4);
            if (u == 0) atomicAdd(&S[b * 128 + n - 128], val);
        }
    }
}

// N3: out[b,m,f] = sum_{n<128} A*w*H + g[m] * sum_{n>=128} A*(1/S_n)*H.
// 256 blocks x 512 thr, four m-columns per block.
// f4 = t&31, ng = t>>5 (16 n-groups x 16 iters; groups 0..7 low, 8..15 high).
__global__ __launch_bounds__(512) void k_out(const float* __restrict__ A,
                                             const float* __restrict__ H,
                                             const float* __restrict__ g,
                                             const float* __restrict__ rs0,
                                             const float* __restrict__ rs1,
                                             const float* __restrict__ S,
                                             float* __restrict__ out) {
    __shared__ float sW[NN];
    __shared__ float sA[4][NN];
    __shared__ float4 sacc[16][4][32];     // 32 KB
    const int blk = blockIdx.x;
    const int b = blk >> 7, mq = blk & 127;
    const int m_base = 4 * mq;
    const int t = threadIdx.x;
    if (t < 128) {
        sW[t] = ((mq < 64) ? rs0 : rs1)[b * NN + t];   // low-row weight half
    } else if (t < 256) {
        sW[t] = 1.f / S[b * 128 + (t - 128)];          // high-row 1/S_n
    } else if (t < 512) {
        // nothing
    }
    if (t < 256) {
        const float4* Ar = (const float4*)(A + (size_t)(b * NN + t) * MM + m_base);
        float4 a = Ar[0];
        sA[0][t] = a.x; sA[1][t] = a.y; sA[2][t] = a.z; sA[3][t] = a.w;
    }
    __syncthreads();
    const int f4 = t & 31, ng = t >> 5;    // ng in [0,16)
    const float4* H4 = (const float4*)H + (size_t)b * NN * 32 + f4;
    float4 A0 = {0.f,0.f,0.f,0.f}, A1 = {0.f,0.f,0.f,0.f};
    float4 A2 = {0.f,0.f,0.f,0.f}, A3 = {0.f,0.f,0.f,0.f};
    const int n0 = ng * 16;
#pragma unroll 8
    for (int i = 0; i < 16; ++i) {
        const int n = n0 + i;
        float w = sW[n];                   // LDS broadcast
        float4 hv = H4[n * 32];            // coalesced 16B/lane
        float c0 = sA[0][n] * w;
        float c1 = sA[1][n] * w;
        float c2 = sA[2][n] * w;
        float c3 = sA[3][n] * w;
        A0.x = fmaf(c0, hv.x, A0.x); A0.y = fmaf(c0, hv.y, A0.y);
        A0.z = fmaf(c0, hv.z, A0.z); A0.w = fmaf(c0, hv.w, A0.w);
        A1.x = fmaf(c1, hv.x, A1.x); A1.y = fmaf(c1, hv.y, A1.y);
        A1.z = fmaf(c1, hv.z, A1.z); A1.w = fmaf(c1, hv.w, A1.w);
        A2.x = fmaf(c2, hv.x, A2.x); A2.y = fmaf(c2, hv.y, A2.y);
        A2.z = fmaf(c2, hv.z, A2.z); A2.w = fmaf(c2, hv.w, A2.w);
        A3.x = fmaf(c3, hv.x, A3.x); A3.y = fmaf(c3, hv.y, A3.y);
        A3.z = fmaf(c3, hv.z, A3.z); A3.w = fmaf(c3, hv.w, A3.w);
    }
    sacc[ng][0][f4] = A0;
    sacc[ng][1][f4] = A1;
    sacc[ng][2][f4] = A2;
    sacc[ng][3][f4] = A3;
    __syncthreads();
    if (t < 128) {
        const int ml = t >> 5, fb = t & 31;
        float4 lo = {0.f,0.f,0.f,0.f}, hi = {0.f,0.f,0.f,0.f};
#pragma unroll
        for (int j = 0; j < 8; ++j) {
            float4 vl = sacc[j][ml][fb];
            float4 vh = sacc[8 + j][ml][fb];
            lo.x += vl.x; lo.y += vl.y; lo.z += vl.z; lo.w += vl.w;
            hi.x += vh.x; hi.y += vh.y; hi.z += vh.z; hi.w += vh.w;
        }
        const int m = m_base + ml;
        const float eE = g[b * MM + m];    // = exp(eLow[m])
        float4 r;
        r.x = lo.x + eE * hi.x;
        r.y = lo.y + eE * hi.y;
        r.z = lo.z + eE * hi.z;
        r.w = lo.w + eE * hi.w;
        ((float4*)out)[((size_t)b * MM + m) * 32 + fb] = r;
    }
}

extern "C" void kernel_launch(void* const* d_in, const int* in_sizes, int n_in,
                              void* d_out, int out_size, void* d_ws, size_t ws_size,
                              hipStream_t stream) {
    const float* X = (const float*)d_in[0];
    const float* A = (const float*)d_in[1];
    const float* W = (const float*)d_in[2];
    const float* a = (const float*)d_in[3];
    float* out = (float*)d_out;
    float* ws = (float*)d_ws;

    float* H   = ws;            // B*N*OUTF = 65536
    float* h0  = ws + 65536;    // 512
    float* h1  = ws + 66048;    // 512
    float* g   = ws + 66560;    // B*M = 1024
    float* rs0 = ws + 67584;    // B*N = 512 (low halves used)
    float* rs1 = ws + 68096;    // B*N = 512
    float* S   = ws + 68608;    // B*128 = 256 (high-row softmax denominators)

    k_gemm<<<256, 512, 0, stream>>>(X, A, W, a, H, h0, h1, rs0, rs1, S);
    k_emg<<<64, 512, 0, stream>>>(A, h0, h1, g, S);
    k_out<<<256, 512, 0, stream>>>(A, H, g, rs0, rs1, S, out);
}